// Round 10
// baseline (57.464 us; speedup 1.0000x reference)
//
#include <hip/hip_runtime.h>
#include <math.h>

typedef unsigned char u8;
typedef unsigned int u32;
typedef __attribute__((ext_vector_type(8))) int i32x8;
typedef __attribute__((ext_vector_type(4))) float f32x4;

#define SC1 0x7F7F7F7F   // e8m0 scale bytes = 127 -> 2^0 = 1.0
#define CPB 1024         // cols per block
#define NCT 16           // col-tiles (64 cols each) per block

// ---------- helpers ----------

__device__ __forceinline__ u32 ordf(float f) {
    u32 u = __float_as_uint(f);
    return (u & 0x80000000u) ? ~u : (u | 0x80000000u);
}
__device__ __forceinline__ float unordf(u32 u) {
    u = (u & 0x80000000u) ? (u & 0x7FFFFFFFu) : ~u;
    return __uint_as_float(u);
}

// f32 -> OCP e4m3fn with RNE. Assumes finite |x| <= 1.
__device__ __forceinline__ u32 f2e4m3(float x) {
    u32 u = __float_as_uint(x);
    u32 sgn = (u >> 24) & 0x80u;
    int ne = (int)((u >> 23) & 0xFF) - 120;   // e4m3 biased exponent
    if (ne >= 1) {
        u32 m = u & 0x7FFFFFu;
        u32 keep = m >> 20;
        u32 rest = m & 0xFFFFFu;
        keep += (rest > 0x80000u) || (rest == 0x80000u && (keep & 1u));
        if (keep == 8u) { keep = 0u; ne += 1; }
        return sgn | ((u32)ne << 3) | keep;
    }
    float ax = __uint_as_float(u & 0x7FFFFFFFu);
    u32 f = (u32)__builtin_rintf(ax * 512.0f);
    if (f >= 8u) return sgn | 0x08u;
    return sgn | f;
}

// async global->LDS, 16B per lane (dest = wave-uniform base + lane*16)
__device__ __forceinline__ void gload_lds16(const void* gsrc, void* ldst) {
    __builtin_amdgcn_global_load_lds(
        (const __attribute__((address_space(1))) void*)gsrc,
        (__attribute__((address_space(3))) void*)ldst,
        16, 0, 0);
}

__device__ __forceinline__ i32x8 ldfrag(const char* plo, const char* phi) {
    int4 lo = *(const int4*)plo;
    int4 hi = *(const int4*)phi;
    i32x8 r = {lo.x, lo.y, lo.z, lo.w, hi.x, hi.y, hi.z, hi.w};
    return r;
}

#define BARRIER do { __builtin_amdgcn_sched_barrier(0); \
                     __builtin_amdgcn_s_barrier(); \
                     __builtin_amdgcn_sched_barrier(0); } while (0)
#define VMCNT(n) do { asm volatile("s_waitcnt vmcnt(" #n ")" ::: "memory"); \
                      __builtin_amdgcn_sched_barrier(0); } while (0)

// ---------- kernel 1: normalize rows -> fp8 e4m3; init rowmax ----------

__global__ __launch_bounds__(256) void norm_kernel(
    const float* __restrict__ feat, const float* __restrict__ memf,
    u8* __restrict__ fb, u8* __restrict__ mb, u32* __restrict__ rowmax,
    int N, int M, int D)
{
    const int lane = threadIdx.x & 63;
    const int wid  = threadIdx.x >> 6;
    const int rid  = blockIdx.x * 4 + wid;
    if (rid >= N + M) return;

    const float* src;
    u8* dst;
    if (rid < N) { src = feat + (size_t)rid * D; dst = fb + (size_t)rid * D; }
    else         { src = memf + (size_t)(rid - N) * D; dst = mb + (size_t)(rid - N) * D; }

    float4 v0 = *(const float4*)(src + lane * 8);
    float4 v1 = *(const float4*)(src + lane * 8 + 4);
    float ss = v0.x*v0.x + v0.y*v0.y + v0.z*v0.z + v0.w*v0.w
             + v1.x*v1.x + v1.y*v1.y + v1.z*v1.z + v1.w*v1.w;
    #pragma unroll
    for (int m = 1; m <= 32; m <<= 1) ss += __shfl_xor(ss, m);

    float inv = 1.0f / fmaxf(sqrtf(ss), 1e-8f);

    u32 w0 =  f2e4m3(v0.x * inv)        | (f2e4m3(v0.y * inv) << 8)
           | (f2e4m3(v0.z * inv) << 16) | (f2e4m3(v0.w * inv) << 24);
    u32 w1 =  f2e4m3(v1.x * inv)        | (f2e4m3(v1.y * inv) << 8)
           | (f2e4m3(v1.z * inv) << 16) | (f2e4m3(v1.w * inv) << 24);
    *(uint2*)(dst + lane * 8) = make_uint2(w0, w1);

    if (rid < N && lane == 0) rowmax[rid] = 0u;   // below any real sim
}

// ---------- kernel 2: A-in-regs (128-row waves) + dbuf-B MX-fp8 GEMM ----------
// Block = 256-row stripe x 1024 cols, 16 col-tiles of 64. Grid (8,32)=256 = 1/CU.
// 4 waves (2 row-halves x 2 col-halves); per wave 128 rows x 32 cols per ct.
// A: 128 rows x K=512 fp8 in regs: areg[8][4] i32x8 = 256 VGPR (1 wave/SIMD,
// launch_bounds(256,1)). LDS-read volume halves vs 64-row waves (4 B/cell).
// B: 64-col tile = 32KB, double-buffered (64KB LDS). Per-ct ledger:
//   BARRIER (WAR: prev compute done) ; STAGE(ct+1)->other buf ; VMCNT(8)
//   (certifies stage(ct), issued one full compute earlier) ; BARRIER ; compute.
// No vmcnt(0) in the loop except the last tile. Frag layout + XOR swizzle
// (byte ^= (row&7)<<4, pre-swizzled global source) as verified r7-r9.
// MFMA: mfma_scale_f32_16x16x128_f8f6f4, fmt=0 (e4m3), scales = 1.0.

#define STAGE_B(ct, bufo) do { \
    _Pragma("unroll") \
    for (int kt_ = 0; kt_ < 4; ++kt_) { \
      gload_lds16(gBs + (size_t)(ct) * 64 * D + kt_ * 128, \
                  &L[(bufo) + kt_ * 8192 + tid * 16]); \
      gload_lds16(gBs + (size_t)(ct) * 64 * D + (size_t)32 * D + kt_ * 128, \
                  &L[(bufo) + kt_ * 8192 + 4096 + tid * 16]); \
    } } while (0)

__global__ __launch_bounds__(256, 1) void gemm_max_kernel(
    const u8* __restrict__ fb, const u8* __restrict__ mb,
    u32* __restrict__ rowmax, int N, int M, int D)
{
    __shared__ __align__(16) u8 L[65536];   // B double buffer: 2 x 32 KB

    const int tid  = threadIdx.x;
    const int lane = tid & 63;
    const int wid  = tid >> 6;
    const int wwr  = wid >> 1;      // row-half (0..1): rows wwr*128..+127
    const int wwc  = wid & 1;       // col-half (0..1): cols wwc*32..+31
    const int l15  = lane & 15;
    const int l4   = lane >> 4;
    const int n0   = blockIdx.y * 256;
    const int m0   = blockIdx.x * CPB;

    // B staging: thread covers slots tid and tid+256 of each 8KB kt-slab
    const int srow   = tid >> 3;                       // 0..31
    const int schunk = (tid & 7) ^ (srow & 7);         // pre-swizzled chunk
    const u8* gBs = mb + (size_t)(m0 + srow) * D + schunk * 16;

    // B ds_read: per-lane swizzled k-offsets (two b128 per frag)
    const int s   = (l15 & 7) << 4;
    const int oLo = (l4 * 32) ^ s;
    const int oHi = (l4 * 32 + 16) ^ s;
    const char* Lb = (const char*)L;
    const int rdoff = (wwc * 32 + l15) * 128;          // row base within slab

    // ---- prologue: issue B stage for ct=0, then load A stripe into regs ----
    STAGE_B(0, 0);

    const u8* gA = fb + (size_t)(n0 + wwr * 128 + l15) * D + l4 * 32;
    i32x8 areg[8][4];   // [row-frag i][k-tile kt] = 256 VGPR
    #pragma unroll
    for (int i = 0; i < 8; ++i)
        #pragma unroll
        for (int kt = 0; kt < 4; ++kt)
            areg[i][kt] = *(const i32x8*)(gA + (size_t)(i * 16) * D + kt * 128);

    f32x4 acc[8][2] = {};
    float vmax[8][4];
    #pragma unroll
    for (int i = 0; i < 8; ++i)
        #pragma unroll
        for (int rr = 0; rr < 4; ++rr) vmax[i][rr] = -1e30f;

    #pragma unroll 2
    for (int ct = 0; ct < NCT; ++ct) {
        const int cur = (ct & 1) * 32768;

        BARRIER;   // WAR: all waves done reading buf[cur^1] (ct-1's tile)
        if (ct + 1 < NCT) { STAGE_B(ct + 1, 32768 - cur); VMCNT(8); }
        else              { VMCNT(0); }
        BARRIER;   // buf[cur] certified block-wide

        const char* Bt = Lb + cur + rdoff;
        #pragma unroll
        for (int kt = 0; kt < 4; ++kt) {
            i32x8 bf0 = ldfrag(Bt + kt * 8192 + oLo,        Bt + kt * 8192 + oHi);
            i32x8 bf1 = ldfrag(Bt + kt * 8192 + 2048 + oLo, Bt + kt * 8192 + 2048 + oHi);
            #pragma unroll
            for (int i = 0; i < 8; ++i) {
                acc[i][0] = __builtin_amdgcn_mfma_scale_f32_16x16x128_f8f6f4(
                    areg[i][kt], bf0, acc[i][0], 0, 0, 0, SC1, 0, SC1);
                acc[i][1] = __builtin_amdgcn_mfma_scale_f32_16x16x128_f8f6f4(
                    areg[i][kt], bf1, acc[i][1], 0, 0, 0, SC1, 0, SC1);
            }
        }

        // fold this col-tile into running max; reset acc
        #pragma unroll
        for (int i = 0; i < 8; ++i)
            #pragma unroll
            for (int rr = 0; rr < 4; ++rr)
                vmax[i][rr] = fmaxf(vmax[i][rr],
                                    fmaxf(acc[i][0][rr], acc[i][1][rr]));
        #pragma unroll
        for (int i = 0; i < 8; ++i) {
            acc[i][0] = (f32x4)0.0f;
            acc[i][1] = (f32x4)0.0f;
        }
    }

    // ---- epilogue: cross-lane + cross-wave max reduce; one atomic/row ----
    BARRIER;                      // protect L reuse
    float* red = (float*)L;       // [256][2]
    #pragma unroll
    for (int i = 0; i < 8; ++i) {
        #pragma unroll
        for (int rr = 0; rr < 4; ++rr) {
            float v = vmax[i][rr];
            v = fmaxf(v, __shfl_xor(v, 1));
            v = fmaxf(v, __shfl_xor(v, 2));
            v = fmaxf(v, __shfl_xor(v, 4));
            v = fmaxf(v, __shfl_xor(v, 8));
            if (l15 == 0) {
                int rloc = wwr * 128 + i * 16 + l4 * 4 + rr;
                red[rloc * 2 + wwc] = v;
            }
        }
    }
    __syncthreads();
    if (tid < 256) {
        float v = fmaxf(red[tid * 2 + 0], red[tid * 2 + 1]);
        atomicMax(&rowmax[n0 + tid], ordf(v));
    }
}

// ---------- kernel 3a: BCE + novelty weight, per-block partial sums ----------

__global__ __launch_bounds__(256) void finalize1_kernel(
    const float* __restrict__ pred, const float* __restrict__ targ,
    const u32* __restrict__ rowmax, float* __restrict__ partial, int N)
{
    __shared__ float ws4[4];
    const int tid = threadIdx.x;
    const int i = blockIdx.x * 256 + tid;

    float sv = 0.f;
    if (i < N) {
        float x = pred[i];
        float t = targ[i];
        float bl = fmaxf(x, 0.f) + log1pf(expf(-fabsf(x))) - x * t;
        float ms = unordf(rowmax[i]);
        sv = bl * (1.0f + 2.0f * (1.0f - ms));
    }
    #pragma unroll
    for (int m = 1; m <= 32; m <<= 1) sv += __shfl_xor(sv, m);
    if ((tid & 63) == 0) ws4[tid >> 6] = sv;
    __syncthreads();
    if (tid == 0) partial[blockIdx.x] = ws4[0] + ws4[1] + ws4[2] + ws4[3];
}

// ---------- kernel 3b: final reduce ----------

__global__ __launch_bounds__(64) void finalize2_kernel(
    const float* __restrict__ partial, float* __restrict__ out, int nb, int N)
{
    float sv = 0.f;
    for (int i = threadIdx.x; i < nb; i += 64) sv += partial[i];
    #pragma unroll
    for (int m = 1; m <= 32; m <<= 1) sv += __shfl_xor(sv, m);
    if (threadIdx.x == 0) out[0] = sv / (float)N;
}

// ---------- launch ----------

extern "C" void kernel_launch(void* const* d_in, const int* in_sizes, int n_in,
                              void* d_out, int out_size, void* d_ws, size_t ws_size,
                              hipStream_t stream) {
    const float* pred = (const float*)d_in[0];
    const float* targ = (const float*)d_in[1];
    const float* feat = (const float*)d_in[2];
    const float* memf = (const float*)d_in[3];
    const int N = in_sizes[0];
    const int D = in_sizes[2] / N;
    const int M = in_sizes[3] / D;
    float* out = (float*)d_out;

    u8* fb8 = (u8*)d_ws;                           // N*D fp8
    u8* mb8 = fb8 + (size_t)N * D;                 // M*D fp8
    u32* rowmax = (u32*)(mb8 + (size_t)M * D);     // N u32
    float* partial = (float*)(rowmax + N);         // nb floats

    const int rows = N + M;
    const int nb = (N + 255) / 256;
    norm_kernel<<<dim3((rows + 3) / 4), dim3(256), 0, stream>>>(
        feat, memf, fb8, mb8, rowmax, N, M, D);
    gemm_max_kernel<<<dim3(M / CPB, N / 256), dim3(256), 0, stream>>>(
        fb8, mb8, rowmax, N, M, D);
    finalize1_kernel<<<dim3(nb), dim3(256), 0, stream>>>(
        pred, targ, rowmax, partial, N);
    finalize2_kernel<<<dim3(1), dim3(64), 0, stream>>>(partial, out, nb, N);
}

// Round 11
// 57.287 us; speedup vs baseline: 1.0031x; 1.0031x over previous
//
#include <hip/hip_runtime.h>
#include <math.h>

typedef unsigned char u8;
typedef unsigned int u32;
typedef __attribute__((ext_vector_type(8))) int i32x8;
typedef __attribute__((ext_vector_type(4))) float f32x4;

#define SC1 0x7F7F7F7F   // e8m0 scale bytes = 127 -> 2^0 = 1.0
#define CPB 1024         // cols per block
#define NCT 16           // col-tiles (64 cols each) per block

// ---------- helpers ----------

__device__ __forceinline__ u32 ordf(float f) {
    u32 u = __float_as_uint(f);
    return (u & 0x80000000u) ? ~u : (u | 0x80000000u);
}
__device__ __forceinline__ float unordf(u32 u) {
    u = (u & 0x80000000u) ? (u & 0x7FFFFFFFu) : ~u;
    return __uint_as_float(u);
}

// f32 -> OCP e4m3fn with RNE. Assumes finite |x| <= 1.
__device__ __forceinline__ u32 f2e4m3(float x) {
    u32 u = __float_as_uint(x);
    u32 sgn = (u >> 24) & 0x80u;
    int ne = (int)((u >> 23) & 0xFF) - 120;   // e4m3 biased exponent
    if (ne >= 1) {
        u32 m = u & 0x7FFFFFu;
        u32 keep = m >> 20;
        u32 rest = m & 0xFFFFFu;
        keep += (rest > 0x80000u) || (rest == 0x80000u && (keep & 1u));
        if (keep == 8u) { keep = 0u; ne += 1; }
        return sgn | ((u32)ne << 3) | keep;
    }
    float ax = __uint_as_float(u & 0x7FFFFFFFu);
    u32 f = (u32)__builtin_rintf(ax * 512.0f);
    if (f >= 8u) return sgn | 0x08u;
    return sgn | f;
}

// async global->LDS, 16B per lane (dest = wave-uniform base + lane*16)
__device__ __forceinline__ void gload_lds16(const void* gsrc, void* ldst) {
    __builtin_amdgcn_global_load_lds(
        (const __attribute__((address_space(1))) void*)gsrc,
        (__attribute__((address_space(3))) void*)ldst,
        16, 0, 0);
}

__device__ __forceinline__ i32x8 ldfrag(const char* plo, const char* phi) {
    int4 lo = *(const int4*)plo;
    int4 hi = *(const int4*)phi;
    i32x8 r = {lo.x, lo.y, lo.z, lo.w, hi.x, hi.y, hi.z, hi.w};
    return r;
}

#define BARRIER do { __builtin_amdgcn_sched_barrier(0); \
                     __builtin_amdgcn_s_barrier(); \
                     __builtin_amdgcn_sched_barrier(0); } while (0)
#define VMCNT(n) do { asm volatile("s_waitcnt vmcnt(" #n ")" ::: "memory"); \
                      __builtin_amdgcn_sched_barrier(0); } while (0)

// ---------- kernel 1: normalize rows -> fp8 e4m3; init rowmax ----------

__global__ __launch_bounds__(256) void norm_kernel(
    const float* __restrict__ feat, const float* __restrict__ memf,
    u8* __restrict__ fb, u8* __restrict__ mb, u32* __restrict__ rowmax,
    int N, int M, int D)
{
    const int lane = threadIdx.x & 63;
    const int wid  = threadIdx.x >> 6;
    const int rid  = blockIdx.x * 4 + wid;
    if (rid >= N + M) return;

    const float* src;
    u8* dst;
    if (rid < N) { src = feat + (size_t)rid * D; dst = fb + (size_t)rid * D; }
    else         { src = memf + (size_t)(rid - N) * D; dst = mb + (size_t)(rid - N) * D; }

    float4 v0 = *(const float4*)(src + lane * 8);
    float4 v1 = *(const float4*)(src + lane * 8 + 4);
    float ss = v0.x*v0.x + v0.y*v0.y + v0.z*v0.z + v0.w*v0.w
             + v1.x*v1.x + v1.y*v1.y + v1.z*v1.z + v1.w*v1.w;
    #pragma unroll
    for (int m = 1; m <= 32; m <<= 1) ss += __shfl_xor(ss, m);

    float inv = 1.0f / fmaxf(sqrtf(ss), 1e-8f);

    u32 w0 =  f2e4m3(v0.x * inv)        | (f2e4m3(v0.y * inv) << 8)
           | (f2e4m3(v0.z * inv) << 16) | (f2e4m3(v0.w * inv) << 24);
    u32 w1 =  f2e4m3(v1.x * inv)        | (f2e4m3(v1.y * inv) << 8)
           | (f2e4m3(v1.z * inv) << 16) | (f2e4m3(v1.w * inv) << 24);
    *(uint2*)(dst + lane * 8) = make_uint2(w0, w1);

    if (rid < N && lane == 0) rowmax[rid] = 0u;   // below any real sim
}

// ---------- kernel 2: A-in-regs (64-row waves) + dbuf-B MX-fp8 GEMM ----------
// r9 geometry + r10 ledger (unconfounded): block = 128-row stripe x 1024 cols,
// 16 col-tiles of 64. Grid (8,64) = 512 = 2 blocks/CU -> 2 waves/SIMD (the
// r10 regression was 1 wave/SIMD: nothing to overlap with).
// 4 waves (2 row-halves x 2 col-halves); per wave per ct: 64 rows x 32 cols.
// A: 64 rows x K=512 fp8 in regs: areg[4][4] i32x8 = 128 VGPR.
// B: 64-col tile = 32KB (4 kt-slabs x [64 rows][128B]), double-buffered.
// Per-ct ledger: BARRIER (WAR: prev compute done); STAGE(ct+1)->other buf;
// VMCNT(8) certifies stage(ct) (issued one full compute phase earlier);
// BARRIER; compute. No vmcnt(0) in-loop except last tile.
// Frag layout + XOR swizzle (byte ^= (row&7)<<4, pre-swizzled global source)
// as verified r7-r10. MFMA: mfma_scale_f32_16x16x128_f8f6f4, e4m3, scale 1.0.

#define STAGE_B(ct, bufo) do { \
    _Pragma("unroll") \
    for (int kt_ = 0; kt_ < 4; ++kt_) { \
      gload_lds16(gBs + (size_t)(ct) * 64 * D + kt_ * 128, \
                  &L[(bufo) + kt_ * 8192 + tid * 16]); \
      gload_lds16(gBs + (size_t)(ct) * 64 * D + (size_t)32 * D + kt_ * 128, \
                  &L[(bufo) + kt_ * 8192 + 4096 + tid * 16]); \
    } } while (0)

__global__ __launch_bounds__(256, 2) void gemm_max_kernel(
    const u8* __restrict__ fb, const u8* __restrict__ mb,
    u32* __restrict__ rowmax, int N, int M, int D)
{
    __shared__ __align__(16) u8 L[65536];   // B double buffer: 2 x 32 KB

    const int tid  = threadIdx.x;
    const int lane = tid & 63;
    const int wid  = tid >> 6;
    const int wwr  = wid >> 1;      // row-half (0..1): rows wwr*64..+63
    const int wwc  = wid & 1;       // col-half (0..1): cols wwc*32..+31
    const int l15  = lane & 15;
    const int l4   = lane >> 4;
    const int n0   = blockIdx.y * 128;
    const int m0   = blockIdx.x * CPB;

    // B staging: thread covers rows srow and srow+32 of each 8KB kt-slab
    const int srow   = tid >> 3;                       // 0..31
    const int schunk = (tid & 7) ^ (srow & 7);         // pre-swizzled chunk
    const u8* gBs = mb + (size_t)(m0 + srow) * D + schunk * 16;

    // B ds_read: per-lane swizzled k-offsets (two b128 per frag)
    const int s   = (l15 & 7) << 4;
    const int oLo = (l4 * 32) ^ s;
    const int oHi = (l4 * 32 + 16) ^ s;
    const char* Lb = (const char*)L;
    const int rdoff = (wwc * 32 + l15) * 128;          // row base within slab

    // ---- prologue: issue B stage for ct=0, then load A stripe into regs ----
    STAGE_B(0, 0);

    const u8* gA = fb + (size_t)(n0 + wwr * 64 + l15) * D + l4 * 32;
    i32x8 areg[4][4];   // [row-frag i][k-tile kt] = 128 VGPR
    #pragma unroll
    for (int i = 0; i < 4; ++i)
        #pragma unroll
        for (int kt = 0; kt < 4; ++kt)
            areg[i][kt] = *(const i32x8*)(gA + (size_t)(i * 16) * D + kt * 128);

    f32x4 acc[4][2] = {};
    float vmax[4][4];
    #pragma unroll
    for (int i = 0; i < 4; ++i)
        #pragma unroll
        for (int rr = 0; rr < 4; ++rr) vmax[i][rr] = -1e30f;

    #pragma unroll 2
    for (int ct = 0; ct < NCT; ++ct) {
        const int cur = (ct & 1) * 32768;

        BARRIER;   // WAR: all waves done reading buf[cur^1] (tile ct-1)
        if (ct + 1 < NCT) { STAGE_B(ct + 1, 32768 - cur); VMCNT(8); }
        else              { VMCNT(0); }
        BARRIER;   // buf[cur] certified block-wide

        const char* Bt = Lb + cur + rdoff;
        #pragma unroll
        for (int kt = 0; kt < 4; ++kt) {
            i32x8 bf0 = ldfrag(Bt + kt * 8192 + oLo,        Bt + kt * 8192 + oHi);
            i32x8 bf1 = ldfrag(Bt + kt * 8192 + 2048 + oLo, Bt + kt * 8192 + 2048 + oHi);
            #pragma unroll
            for (int i = 0; i < 4; ++i) {
                acc[i][0] = __builtin_amdgcn_mfma_scale_f32_16x16x128_f8f6f4(
                    areg[i][kt], bf0, acc[i][0], 0, 0, 0, SC1, 0, SC1);
                acc[i][1] = __builtin_amdgcn_mfma_scale_f32_16x16x128_f8f6f4(
                    areg[i][kt], bf1, acc[i][1], 0, 0, 0, SC1, 0, SC1);
            }
        }

        // fold this col-tile into running max; reset acc
        #pragma unroll
        for (int i = 0; i < 4; ++i)
            #pragma unroll
            for (int rr = 0; rr < 4; ++rr)
                vmax[i][rr] = fmaxf(vmax[i][rr],
                                    fmaxf(acc[i][0][rr], acc[i][1][rr]));
        #pragma unroll
        for (int i = 0; i < 4; ++i) {
            acc[i][0] = (f32x4)0.0f;
            acc[i][1] = (f32x4)0.0f;
        }
    }

    // ---- epilogue: cross-lane + cross-wave max reduce; one atomic/row ----
    BARRIER;                      // protect L reuse
    float* red = (float*)L;       // [128][2]
    #pragma unroll
    for (int i = 0; i < 4; ++i) {
        #pragma unroll
        for (int rr = 0; rr < 4; ++rr) {
            float v = vmax[i][rr];
            v = fmaxf(v, __shfl_xor(v, 1));
            v = fmaxf(v, __shfl_xor(v, 2));
            v = fmaxf(v, __shfl_xor(v, 4));
            v = fmaxf(v, __shfl_xor(v, 8));
            if (l15 == 0) {
                int rloc = wwr * 64 + i * 16 + l4 * 4 + rr;
                red[rloc * 2 + wwc] = v;
            }
        }
    }
    __syncthreads();
    if (tid < 128) {
        float v = fmaxf(red[tid * 2 + 0], red[tid * 2 + 1]);
        atomicMax(&rowmax[n0 + tid], ordf(v));
    }
}

// ---------- kernel 3a: BCE + novelty weight, per-block partial sums ----------

__global__ __launch_bounds__(256) void finalize1_kernel(
    const float* __restrict__ pred, const float* __restrict__ targ,
    const u32* __restrict__ rowmax, float* __restrict__ partial, int N)
{
    __shared__ float ws4[4];
    const int tid = threadIdx.x;
    const int i = blockIdx.x * 256 + tid;

    float sv = 0.f;
    if (i < N) {
        float x = pred[i];
        float t = targ[i];
        float bl = fmaxf(x, 0.f) + log1pf(expf(-fabsf(x))) - x * t;
        float ms = unordf(rowmax[i]);
        sv = bl * (1.0f + 2.0f * (1.0f - ms));
    }
    #pragma unroll
    for (int m = 1; m <= 32; m <<= 1) sv += __shfl_xor(sv, m);
    if ((tid & 63) == 0) ws4[tid >> 6] = sv;
    __syncthreads();
    if (tid == 0) partial[blockIdx.x] = ws4[0] + ws4[1] + ws4[2] + ws4[3];
}

// ---------- kernel 3b: final reduce ----------

__global__ __launch_bounds__(64) void finalize2_kernel(
    const float* __restrict__ partial, float* __restrict__ out, int nb, int N)
{
    float sv = 0.f;
    for (int i = threadIdx.x; i < nb; i += 64) sv += partial[i];
    #pragma unroll
    for (int m = 1; m <= 32; m <<= 1) sv += __shfl_xor(sv, m);
    if (threadIdx.x == 0) out[0] = sv / (float)N;
}

// ---------- launch ----------

extern "C" void kernel_launch(void* const* d_in, const int* in_sizes, int n_in,
                              void* d_out, int out_size, void* d_ws, size_t ws_size,
                              hipStream_t stream) {
    const float* pred = (const float*)d_in[0];
    const float* targ = (const float*)d_in[1];
    const float* feat = (const float*)d_in[2];
    const float* memf = (const float*)d_in[3];
    const int N = in_sizes[0];
    const int D = in_sizes[2] / N;
    const int M = in_sizes[3] / D;
    float* out = (float*)d_out;

    u8* fb8 = (u8*)d_ws;                           // N*D fp8
    u8* mb8 = fb8 + (size_t)N * D;                 // M*D fp8
    u32* rowmax = (u32*)(mb8 + (size_t)M * D);     // N u32
    float* partial = (float*)(rowmax + N);         // nb floats

    const int rows = N + M;
    const int nb = (N + 255) / 256;
    norm_kernel<<<dim3((rows + 3) / 4), dim3(256), 0, stream>>>(
        feat, memf, fb8, mb8, rowmax, N, M, D);
    gemm_max_kernel<<<dim3(M / CPB, N / 128), dim3(256), 0, stream>>>(
        fb8, mb8, rowmax, N, M, D);
    finalize1_kernel<<<dim3(nb), dim3(256), 0, stream>>>(
        pred, targ, rowmax, partial, N);
    finalize2_kernel<<<dim3(1), dim3(64), 0, stream>>>(partial, out, nb, N);
}

// Round 12
// 56.317 us; speedup vs baseline: 1.0204x; 1.0172x over previous
//
#include <hip/hip_runtime.h>
#include <math.h>

typedef unsigned char u8;
typedef unsigned int u32;
typedef __attribute__((ext_vector_type(8))) int i32x8;
typedef __attribute__((ext_vector_type(4))) float f32x4;

#define SC1 0x7F7F7F7F   // e8m0 scale bytes = 127 -> 2^0 = 1.0
#define CPB 1024         // cols per block
#define NCT 16           // col-tiles (64 cols each) per block

// ---------- helpers ----------

__device__ __forceinline__ u32 ordf(float f) {
    u32 u = __float_as_uint(f);
    return (u & 0x80000000u) ? ~u : (u | 0x80000000u);
}
__device__ __forceinline__ float unordf(u32 u) {
    u = (u & 0x80000000u) ? (u & 0x7FFFFFFFu) : ~u;
    return __uint_as_float(u);
}

// f32 -> OCP e4m3fn with RNE. Assumes finite |x| <= 1.
__device__ __forceinline__ u32 f2e4m3(float x) {
    u32 u = __float_as_uint(x);
    u32 sgn = (u >> 24) & 0x80u;
    int ne = (int)((u >> 23) & 0xFF) - 120;   // e4m3 biased exponent
    if (ne >= 1) {
        u32 m = u & 0x7FFFFFu;
        u32 keep = m >> 20;
        u32 rest = m & 0xFFFFFu;
        keep += (rest > 0x80000u) || (rest == 0x80000u && (keep & 1u));
        if (keep == 8u) { keep = 0u; ne += 1; }
        return sgn | ((u32)ne << 3) | keep;
    }
    float ax = __uint_as_float(u & 0x7FFFFFFFu);
    u32 f = (u32)__builtin_rintf(ax * 512.0f);
    if (f >= 8u) return sgn | 0x08u;
    return sgn | f;
}

// async global->LDS, 16B per lane (dest = wave-uniform base + lane*16)
__device__ __forceinline__ void gload_lds16(const void* gsrc, void* ldst) {
    __builtin_amdgcn_global_load_lds(
        (const __attribute__((address_space(1))) void*)gsrc,
        (__attribute__((address_space(3))) void*)ldst,
        16, 0, 0);
}

__device__ __forceinline__ i32x8 ldfrag(const char* plo, const char* phi) {
    int4 lo = *(const int4*)plo;
    int4 hi = *(const int4*)phi;
    i32x8 r = {lo.x, lo.y, lo.z, lo.w, hi.x, hi.y, hi.z, hi.w};
    return r;
}

#define BARRIER do { __builtin_amdgcn_sched_barrier(0); \
                     __builtin_amdgcn_s_barrier(); \
                     __builtin_amdgcn_sched_barrier(0); } while (0)
#define VMCNT(n) do { asm volatile("s_waitcnt vmcnt(" #n ")" ::: "memory"); \
                      __builtin_amdgcn_sched_barrier(0); } while (0)

// ---------- kernel 1: normalize rows -> fp8 e4m3; init rowmax ----------

__global__ __launch_bounds__(256) void norm_kernel(
    const float* __restrict__ feat, const float* __restrict__ memf,
    u8* __restrict__ fb, u8* __restrict__ mb, u32* __restrict__ rowmax,
    int N, int M, int D)
{
    const int lane = threadIdx.x & 63;
    const int wid  = threadIdx.x >> 6;
    const int rid  = blockIdx.x * 4 + wid;
    if (rid >= N + M) return;

    const float* src;
    u8* dst;
    if (rid < N) { src = feat + (size_t)rid * D; dst = fb + (size_t)rid * D; }
    else         { src = memf + (size_t)(rid - N) * D; dst = mb + (size_t)(rid - N) * D; }

    float4 v0 = *(const float4*)(src + lane * 8);
    float4 v1 = *(const float4*)(src + lane * 8 + 4);
    float ss = v0.x*v0.x + v0.y*v0.y + v0.z*v0.z + v0.w*v0.w
             + v1.x*v1.x + v1.y*v1.y + v1.z*v1.z + v1.w*v1.w;
    #pragma unroll
    for (int m = 1; m <= 32; m <<= 1) ss += __shfl_xor(ss, m);

    float inv = 1.0f / fmaxf(sqrtf(ss), 1e-8f);

    u32 w0 =  f2e4m3(v0.x * inv)        | (f2e4m3(v0.y * inv) << 8)
           | (f2e4m3(v0.z * inv) << 16) | (f2e4m3(v0.w * inv) << 24);
    u32 w1 =  f2e4m3(v1.x * inv)        | (f2e4m3(v1.y * inv) << 8)
           | (f2e4m3(v1.z * inv) << 16) | (f2e4m3(v1.w * inv) << 24);
    *(uint2*)(dst + lane * 8) = make_uint2(w0, w1);

    if (rid < N && lane == 0) rowmax[rid] = 0u;   // below any real sim
}

// ---------- kernel 2: A-in-regs + TRIPLE-buffered-B MX-fp8 GEMM + row-max ----
// Block = 256 rows x 1024 cols, 512 threads = 8 waves (4 row-halves x 2
// col-halves). Grid (8,32) = 256 = 1 block/CU -> 2 waves/SIMD.
// A: 64 rows x K=512 fp8 per wave in regs: areg[4][4] i32x8 = 128 VGPR.
// B: 64-col tile = 32KB (4 kt-slabs x [64 rows][128B]), TRIPLE-buffered
// (96KB LDS) -> stage(ct+2) issued with TWO compute phases of headroom.
// Per-iter: compute(ct) [buf cur]; BARRIER (all ct & ct-1 reads certified);
// STAGE(ct+2) -> buf of tile ct-1; VMCNT(4) certifies stage(ct+1) (newest 4
// outstanding = stage(ct+2)); BARRIER (block-wide residency).
// Frag layout + XOR swizzle (byte ^= (row&7)<<4, pre-swizzled global source)
// as verified r7-r11. MFMA: mfma_scale_f32_16x16x128_f8f6f4, e4m3, scale 1.0.

#define STAGE_B(ct, bufo) do { \
    _Pragma("unroll") \
    for (int kt_ = 0; kt_ < 4; ++kt_) \
      gload_lds16(gBs + (size_t)(ct) * 64 * D + kt_ * 128, \
                  &L[(bufo) + kt_ * 8192 + tid * 16]); \
  } while (0)

__global__ __launch_bounds__(512, 2) void gemm_max_kernel(
    const u8* __restrict__ fb, const u8* __restrict__ mb,
    u32* __restrict__ rowmax, int N, int M, int D)
{
    __shared__ __align__(16) u8 L[98304];   // B triple buffer: 3 x 32 KB

    const int tid  = threadIdx.x;
    const int lane = tid & 63;
    const int wid  = tid >> 6;
    const int wwr  = wid >> 1;      // row-quarter (0..3): rows wwr*64..+63
    const int wwc  = wid & 1;       // col-half (0..1): cols wwc*32..+31
    const int l15  = lane & 15;
    const int l4   = lane >> 4;
    const int n0   = blockIdx.y * 256;
    const int m0   = blockIdx.x * CPB;

    // B staging: thread covers row srow (0..63), pre-swizzled chunk
    const int srow   = tid >> 3;                       // 0..63
    const int schunk = (tid & 7) ^ (srow & 7);
    const u8* gBs = mb + (size_t)(m0 + srow) * D + schunk * 16;

    // B ds_read: per-lane swizzled k-offsets (two b128 per frag)
    const int s   = (l15 & 7) << 4;
    const int oLo = (l4 * 32) ^ s;
    const int oHi = (l4 * 32 + 16) ^ s;
    const char* Lb = (const char*)L;
    const int rdoff = (wwc * 32 + l15) * 128;          // row base within slab

    // ---- prologue: stage ct=0,1 into buf0,buf1; load A stripe into regs ----
    STAGE_B(0, 0);
    STAGE_B(1, 32768);

    const u8* gA = fb + (size_t)(n0 + wwr * 64 + l15) * D + l4 * 32;
    i32x8 areg[4][4];   // [row-frag i][k-tile kt] = 128 VGPR
    #pragma unroll
    for (int i = 0; i < 4; ++i)
        #pragma unroll
        for (int kt = 0; kt < 4; ++kt)
            areg[i][kt] = *(const i32x8*)(gA + (size_t)(i * 16) * D + kt * 128);

    VMCNT(4);   // drains A-loads + stage(0); leaves stage(1) (newest 4)
    BARRIER;

    f32x4 acc[4][2] = {};
    float vmax[4][4];
    #pragma unroll
    for (int i = 0; i < 4; ++i)
        #pragma unroll
        for (int rr = 0; rr < 4; ++rr) vmax[i][rr] = -1e30f;

    int cur = 0, nxt = 32768, nx2 = 65536;   // rotating buffer offsets

    for (int ct = 0; ct < NCT; ++ct) {
        // ---- compute(ct) from buf[cur]: 4 kt x (2 frag-pair reads + 8 MFMA) --
        const char* Bt = Lb + cur + rdoff;
        #pragma unroll
        for (int kt = 0; kt < 4; ++kt) {
            i32x8 bf0 = ldfrag(Bt + kt * 8192 + oLo,        Bt + kt * 8192 + oHi);
            i32x8 bf1 = ldfrag(Bt + kt * 8192 + 2048 + oLo, Bt + kt * 8192 + 2048 + oHi);
            #pragma unroll
            for (int i = 0; i < 4; ++i) {
                acc[i][0] = __builtin_amdgcn_mfma_scale_f32_16x16x128_f8f6f4(
                    areg[i][kt], bf0, acc[i][0], 0, 0, 0, SC1, 0, SC1);
                acc[i][1] = __builtin_amdgcn_mfma_scale_f32_16x16x128_f8f6f4(
                    areg[i][kt], bf1, acc[i][1], 0, 0, 0, SC1, 0, SC1);
            }
        }

        // fold this col-tile into running max; reset acc
        #pragma unroll
        for (int i = 0; i < 4; ++i)
            #pragma unroll
            for (int rr = 0; rr < 4; ++rr)
                vmax[i][rr] = fmaxf(vmax[i][rr],
                                    fmaxf(acc[i][0][rr], acc[i][1][rr]));
        #pragma unroll
        for (int i = 0; i < 4; ++i) {
            acc[i][0] = (f32x4)0.0f;
            acc[i][1] = (f32x4)0.0f;
        }

        BARRIER;   // all waves' reads of tiles ct (and ct-1) certified

        // ---- stage ct+2 over tile ct-1's buffer; counted wait on ct+1 ----
        if (ct + 2 < NCT) { STAGE_B(ct + 2, nx2); VMCNT(4); }
        else if (ct + 1 < NCT) { VMCNT(0); }
        BARRIER;   // buf[nxt] certified block-wide

        int t = cur; cur = nxt; nxt = nx2; nx2 = t;   // rotate
    }

    // ---- epilogue: cross-lane + cross-wave max reduce; one atomic/row ----
    float* red = (float*)L;       // [256][2], safe after final BARRIER
    #pragma unroll
    for (int i = 0; i < 4; ++i) {
        #pragma unroll
        for (int rr = 0; rr < 4; ++rr) {
            float v = vmax[i][rr];
            v = fmaxf(v, __shfl_xor(v, 1));
            v = fmaxf(v, __shfl_xor(v, 2));
            v = fmaxf(v, __shfl_xor(v, 4));
            v = fmaxf(v, __shfl_xor(v, 8));
            if (l15 == 0) {
                int rloc = wwr * 64 + i * 16 + l4 * 4 + rr;
                red[rloc * 2 + wwc] = v;
            }
        }
    }
    __syncthreads();
    if (tid < 256) {
        float v = fmaxf(red[tid * 2 + 0], red[tid * 2 + 1]);
        atomicMax(&rowmax[n0 + tid], ordf(v));
    }
}

// ---------- kernel 3a: BCE + novelty weight, per-block partial sums ----------

__global__ __launch_bounds__(256) void finalize1_kernel(
    const float* __restrict__ pred, const float* __restrict__ targ,
    const u32* __restrict__ rowmax, float* __restrict__ partial, int N)
{
    __shared__ float ws4[4];
    const int tid = threadIdx.x;
    const int i = blockIdx.x * 256 + tid;

    float sv = 0.f;
    if (i < N) {
        float x = pred[i];
        float t = targ[i];
        float bl = fmaxf(x, 0.f) + log1pf(expf(-fabsf(x))) - x * t;
        float ms = unordf(rowmax[i]);
        sv = bl * (1.0f + 2.0f * (1.0f - ms));
    }
    #pragma unroll
    for (int m = 1; m <= 32; m <<= 1) sv += __shfl_xor(sv, m);
    if ((tid & 63) == 0) ws4[tid >> 6] = sv;
    __syncthreads();
    if (tid == 0) partial[blockIdx.x] = ws4[0] + ws4[1] + ws4[2] + ws4[3];
}

// ---------- kernel 3b: final reduce ----------

__global__ __launch_bounds__(64) void finalize2_kernel(
    const float* __restrict__ partial, float* __restrict__ out, int nb, int N)
{
    float sv = 0.f;
    for (int i = threadIdx.x; i < nb; i += 64) sv += partial[i];
    #pragma unroll
    for (int m = 1; m <= 32; m <<= 1) sv += __shfl_xor(sv, m);
    if (threadIdx.x == 0) out[0] = sv / (float)N;
}

// ---------- launch ----------

extern "C" void kernel_launch(void* const* d_in, const int* in_sizes, int n_in,
                              void* d_out, int out_size, void* d_ws, size_t ws_size,
                              hipStream_t stream) {
    const float* pred = (const float*)d_in[0];
    const float* targ = (const float*)d_in[1];
    const float* feat = (const float*)d_in[2];
    const float* memf = (const float*)d_in[3];
    const int N = in_sizes[0];
    const int D = in_sizes[2] / N;
    const int M = in_sizes[3] / D;
    float* out = (float*)d_out;

    u8* fb8 = (u8*)d_ws;                           // N*D fp8
    u8* mb8 = fb8 + (size_t)N * D;                 // M*D fp8
    u32* rowmax = (u32*)(mb8 + (size_t)M * D);     // N u32
    float* partial = (float*)(rowmax + N);         // nb floats

    const int rows = N + M;
    const int nb = (N + 255) / 256;
    norm_kernel<<<dim3((rows + 3) / 4), dim3(256), 0, stream>>>(
        feat, memf, fb8, mb8, rowmax, N, M, D);
    gemm_max_kernel<<<dim3(M / CPB, N / 256), dim3(512), 0, stream>>>(
        fb8, mb8, rowmax, N, M, D);
    finalize1_kernel<<<dim3(nb), dim3(256), 0, stream>>>(
        pred, targ, rowmax, partial, N);
    finalize2_kernel<<<dim3(1), dim3(64), 0, stream>>>(partial, out, nb, N);
}